// Round 4
// baseline (1111.621 us; speedup 1.0000x reference)
//
#include <hip/hip_runtime.h>
#include <hip/hip_bf16.h>
#include <cstdint>

#define DEVINL __device__ __forceinline__

using f32x4  = __attribute__((ext_vector_type(4))) float;
using short8 = __attribute__((ext_vector_type(8))) short;
using short4v = __attribute__((ext_vector_type(4))) short;

DEVINL float bf2f(__hip_bfloat16 h){ return __bfloat162float(h); }
DEVINL __hip_bfloat16 f2bf(float f){ return __float2bfloat16(f); }
DEVINL short bfbits(float f){ __hip_bfloat16 h = __float2bfloat16(f); short s; __builtin_memcpy(&s, &h, 2); return s; }
DEVINL float sb2f(short s){ uint32_t u = ((uint32_t)(uint16_t)s) << 16; float f; __builtin_memcpy(&f, &u, 4); return f; }

DEVINL void gl_lds16(const void* g, void* l){
  __builtin_amdgcn_global_load_lds((const __attribute__((address_space(1))) void*)g,
                                   (__attribute__((address_space(3))) void*)l, 16, 0, 0);
}

// ---------------- weight transpose + f32->bf16 cast: dst[C][R] = src[R][C] ----------------
__global__ __launch_bounds__(256) void wtrans(const float* __restrict__ src,
                                              __hip_bfloat16* __restrict__ dst,
                                              int R, int C){
  __shared__ float tile[32][33];
  const int tr0 = blockIdx.y*32, tc0 = blockIdx.x*32;
  const int t = threadIdx.x;
  const int lr = t >> 3, lc = (t & 7) * 4;
  float4 v = *(const float4*)(src + (size_t)(tr0+lr)*C + tc0 + lc);
  tile[lr][lc] = v.x; tile[lr][lc+1] = v.y; tile[lr][lc+2] = v.z; tile[lr][lc+3] = v.w;
  __syncthreads();
  short4v o;
  o[0] = bfbits(tile[lc+0][lr]);
  o[1] = bfbits(tile[lc+1][lr]);
  o[2] = bfbits(tile[lc+2][lr]);
  o[3] = bfbits(tile[lc+3][lr]);
  *(short4v*)(dst + (size_t)(tc0+lr)*R + tr0 + lc) = o;
}

// ---------------- LayerNorm (C=2048), one row per block, bf16 out ----------------
__global__ __launch_bounds__(256) void ln_k(const float* __restrict__ x,
                                            const float* __restrict__ w,
                                            const float* __restrict__ bia,
                                            __hip_bfloat16* __restrict__ out){
  const int row = blockIdx.x, t = threadIdx.x;
  const float* xr = x + (size_t)row*2048;
  float4 v0 = *(const float4*)(xr + t*4);
  float4 v1 = *(const float4*)(xr + 1024 + t*4);
  float s  = v0.x+v0.y+v0.z+v0.w + v1.x+v1.y+v1.z+v1.w;
  float ss = v0.x*v0.x+v0.y*v0.y+v0.z*v0.z+v0.w*v0.w
           + v1.x*v1.x+v1.y*v1.y+v1.z*v1.z+v1.w*v1.w;
  #pragma unroll
  for (int o=1;o<64;o<<=1){ s += __shfl_xor(s,o); ss += __shfl_xor(ss,o); }
  __shared__ float red[8];
  const int wv = t>>6, ln = t&63;
  if (ln==0){ red[wv]=s; red[4+wv]=ss; }
  __syncthreads();
  s = red[0]+red[1]+red[2]+red[3]; ss = red[4]+red[5]+red[6]+red[7];
  const float mu = s*(1.f/2048.f);
  const float inv = rsqrtf(ss*(1.f/2048.f) - mu*mu + 1e-5f);
  {
    float4 wv4 = *(const float4*)(w + t*4);
    float4 bv4 = *(const float4*)(bia + t*4);
    short4v o;
    o[0]=bfbits((v0.x-mu)*inv*wv4.x + bv4.x);
    o[1]=bfbits((v0.y-mu)*inv*wv4.y + bv4.y);
    o[2]=bfbits((v0.z-mu)*inv*wv4.z + bv4.z);
    o[3]=bfbits((v0.w-mu)*inv*wv4.w + bv4.w);
    *(short4v*)(out + (size_t)row*2048 + t*4) = o;
  }
  {
    float4 wv4 = *(const float4*)(w + 1024 + t*4);
    float4 bv4 = *(const float4*)(bia + 1024 + t*4);
    short4v o;
    o[0]=bfbits((v1.x-mu)*inv*wv4.x + bv4.x);
    o[1]=bfbits((v1.y-mu)*inv*wv4.y + bv4.y);
    o[2]=bfbits((v1.z-mu)*inv*wv4.z + bv4.z);
    o[3]=bfbits((v1.w-mu)*inv*wv4.w + bv4.w);
    *(short4v*)(out + (size_t)row*2048 + 1024 + t*4) = o;
  }
}

// ======== deep-pipelined GEMM: C[M,N] = A[M,K]*Bt[N,K]^T, tile BM x 256, BK=64 ========
// 8 waves (2M x 4N), LDS double-buffered, T2 swizzle, counted vmcnt, setprio, T1 swizzle.
// EPI 4: bf16   2: silu->bf16   3: *emul->bf16 (in-place ok)   1: f32 + resid (in-place ok)
template<int EPI, int BM>
__global__ __launch_bounds__(512, 2) void gemm256(
    const __hip_bfloat16* __restrict__ A,
    const __hip_bfloat16* __restrict__ Bt,
    __hip_bfloat16* __restrict__ Cb,
    float* __restrict__ Cf,
    const float* __restrict__ resid,
    const __hip_bfloat16* __restrict__ emul,
    int M, int N, int K, int NTN)
{
  constexpr int MF     = BM/32;        // m-frags per wave (2 waves tile M)
  constexpr int NA     = BM/64;        // A staging groups (8KB each)
  constexpr int ABYTES = BM*128;       // A half bytes (BK=64 -> 128B/row)
  constexpr int TILEB  = ABYTES + 32768;
  constexpr int NLD    = NA + 4;       // gl_lds per stage per thread
  extern __shared__ char smem[];
  const int tid = threadIdx.x, lane = tid & 63, wave = tid >> 6;
  const int l15 = lane & 15, l4 = lane >> 4;
  const int wm = wave >> 2, wn = wave & 3;

  const int nwg = gridDim.x;
  const int id  = blockIdx.x;
  const int swz = (id & 7) * (nwg >> 3) + (id >> 3);
  const int by = swz / NTN, bx = swz % NTN;
  const int row0 = by * BM, col0 = bx * 256;

  const __hip_bfloat16* gptr[NLD];
  int ldsoff[NLD];
  #pragma unroll
  for (int g = 0; g < NLD; ++g){
    const int gg = (g < NA) ? g : g - NA;
    const int r    = gg*64 + (tid >> 3);
    const int colp = (tid & 7) * 16;
    const int coll = colp ^ ((r & 7) << 4);
    if (g < NA) gptr[g] = A  + (size_t)(row0 + r)*K + (coll >> 1);
    else        gptr[g] = Bt + (size_t)(col0 + r)*K + (coll >> 1);
    ldsoff[g] = (g < NA ? 0 : ABYTES) + gg*8192 + tid*16;
  }
  auto STAGE = [&](int bufc, int ktile){
    #pragma unroll
    for (int g = 0; g < NLD; ++g)
      gl_lds16(gptr[g] + (size_t)ktile*64, smem + bufc + ldsoff[g]);
  };

  const int swzm = (l15 & 7) << 4;
  const int aRow = (wm*(BM/2) + l15) * 128;
  const int bRow = ABYTES + (wn*64 + l15) * 128;
  const int colT0 = (l4*16) ^ swzm;
  const int colT1 = (64 + l4*16) ^ swzm;

  f32x4 acc[MF][4] = {};
  const int NT = K >> 6;

  STAGE(0, 0);
  STAGE(TILEB, 1);
  __builtin_amdgcn_sched_barrier(0);
  if constexpr (BM == 256) asm volatile("s_waitcnt vmcnt(8)" ::: "memory");
  else                     asm volatile("s_waitcnt vmcnt(6)" ::: "memory");
  __builtin_amdgcn_s_barrier();
  __builtin_amdgcn_sched_barrier(0);

  for (int t = 0; t < NT; ++t){
    const int bufc = (t & 1) * TILEB;
    #pragma unroll
    for (int ks = 0; ks < 2; ++ks){
      const int ct = (ks == 0) ? colT0 : colT1;
      short8 a[MF], b[4];
      #pragma unroll
      for (int m = 0; m < MF; ++m) a[m] = *(const short8*)(smem + bufc + aRow + m*2048 + ct);
      #pragma unroll
      for (int n = 0; n < 4; ++n) b[n] = *(const short8*)(smem + bufc + bRow + n*2048 + ct);
      __builtin_amdgcn_s_setprio(1);
      #pragma unroll
      for (int m = 0; m < MF; ++m)
        #pragma unroll
        for (int n = 0; n < 4; ++n)
          acc[m][n] = __builtin_amdgcn_mfma_f32_16x16x32_bf16(a[m], b[n], acc[m][n], 0, 0, 0);
      __builtin_amdgcn_s_setprio(0);
    }
    __builtin_amdgcn_sched_barrier(0);
    __builtin_amdgcn_s_barrier();
    __builtin_amdgcn_sched_barrier(0);
    if (t + 2 < NT){
      STAGE(bufc, t + 2);
      __builtin_amdgcn_sched_barrier(0);
      if constexpr (BM == 256) asm volatile("s_waitcnt vmcnt(8)" ::: "memory");
      else                     asm volatile("s_waitcnt vmcnt(6)" ::: "memory");
    } else {
      asm volatile("s_waitcnt vmcnt(0)" ::: "memory");
    }
    __builtin_amdgcn_s_barrier();
    __builtin_amdgcn_sched_barrier(0);
  }

  #pragma unroll
  for (int m = 0; m < MF; ++m){
    const int r0 = row0 + wm*(BM/2) + m*16 + l4*4;
    #pragma unroll
    for (int n = 0; n < 4; ++n){
      const int c = col0 + wn*64 + n*16 + l15;
      #pragma unroll
      for (int j = 0; j < 4; ++j){
        const size_t idx = (size_t)(r0 + j)*N + c;
        const float v = acc[m][n][j];
        if constexpr (EPI == 1)      Cf[idx] = v + resid[idx];
        else if constexpr (EPI == 2) Cb[idx] = f2bf(v / (1.f + __expf(-v)));
        else if constexpr (EPI == 3) Cb[idx] = f2bf(v * bf2f(emul[idx]));
        else                         Cb[idx] = f2bf(v);
      }
    }
  }
}

// ------ RoPE + pack: qkv bf16 (B,T,3C) -> Q,K (BH,T,128) bf16, Vt (BH,128,T) bf16 ------
__global__ __launch_bounds__(256) void ropepack(
    const __hip_bfloat16* __restrict__ qkv, const float* __restrict__ cosT, const float* __restrict__ sinT,
    __hip_bfloat16* __restrict__ Qo, __hip_bfloat16* __restrict__ Ko, __hip_bfloat16* __restrict__ Vo)
{
  __shared__ short vt[128][72];
  const int bh = blockIdx.y, b = bh>>4, h = bh&15;
  const int t0 = blockIdx.x*64, tid = threadIdx.x;
  const int tr = tid>>2, q4 = tid&3;
  const int tg = t0 + tr;
  const __hip_bfloat16* base = qkv + ((size_t)(b*2048 + tg))*6144 + h*128;
  const int pp0 = q4*16;
  float cs[16], sn[16];
  #pragma unroll
  for (int i=0;i<4;i++){
    float4 c4 = *(const float4*)(cosT + (size_t)tg*64 + pp0 + i*4);
    float4 s4 = *(const float4*)(sinT + (size_t)tg*64 + pp0 + i*4);
    cs[i*4+0]=c4.x; cs[i*4+1]=c4.y; cs[i*4+2]=c4.z; cs[i*4+3]=c4.w;
    sn[i*4+0]=s4.x; sn[i*4+1]=s4.y; sn[i*4+2]=s4.z; sn[i*4+3]=s4.w;
  }
  #pragma unroll
  for (int qk=0; qk<2; ++qk){
    const __hip_bfloat16* src = base + qk*2048;
    __hip_bfloat16* dst = (qk==0 ? Qo : Ko) + ((size_t)bh*2048 + tg)*128 + pp0*2;
    short8 ov[4];
    short* o = (short*)ov;
    #pragma unroll
    for (int i=0;i<4;i++){
      short8 v = *(const short8*)(src + pp0*2 + i*8);
      #pragma unroll
      for (int j=0;j<4;j++){
        float xe = sb2f(v[2*j]), xo = sb2f(v[2*j+1]);
        float c = cs[4*i+j], s = sn[4*i+j];
        o[8*i+2*j]   = bfbits(xe*c - xo*s);
        o[8*i+2*j+1] = bfbits(xe*s + xo*c);
      }
    }
    #pragma unroll
    for (int i=0;i<4;i++) *(short8*)(dst + i*8) = ov[i];
  }
  const __hip_bfloat16* vsrc = base + 4096;
  const int vc0 = q4*32;
  #pragma unroll
  for (int i=0;i<4;i++){
    short8 v = *(const short8*)(vsrc + vc0 + i*8);
    #pragma unroll
    for (int j=0;j<8;j++) vt[vc0+i*8+j][tr] = v[j];
  }
  __syncthreads();
  const int d = tid>>1, th0 = (tid&1)*32;
  __hip_bfloat16* vdst = Vo + ((size_t)bh*128 + d)*2048 + t0 + th0;
  #pragma unroll
  for (int i=0;i<4;i++)
    *(short8*)(vdst + i*8) = *(const short8*)(&vt[d][th0 + i*8]);
}

// ------- Flash attention, causal, 4 waves x 32 q-rows, KV step 32, K/V reg-prefetch -------
__global__ __launch_bounds__(256, 2) void attn_k(
    const __hip_bfloat16* __restrict__ Q,
    const __hip_bfloat16* __restrict__ K,
    const __hip_bfloat16* __restrict__ Vt,
    __hip_bfloat16* __restrict__ Y)
{
  __shared__ __hip_bfloat16 pls[4][32][40];
  const int bh = blockIdx.y, b = bh>>4, h = bh&15;
  const int tid = threadIdx.x, lane = tid&63, wave = tid>>6;
  const int qbase = blockIdx.x*128 + wave*32;
  const __hip_bfloat16* Qh = Q + (size_t)bh*2048*128;
  const __hip_bfloat16* Kh = K + (size_t)bh*2048*128;
  const __hip_bfloat16* Vh = Vt + (size_t)bh*128*2048;
  __hip_bfloat16 (*pl)[40] = pls[wave];
  const int l15 = lane & 15, l4 = lane >> 4;

  short8 qf[2][4];
  #pragma unroll
  for (int m=0;m<2;m++)
    #pragma unroll
    for (int kc=0;kc<4;kc++)
      qf[m][kc] = *(const short8*)(Qh + (size_t)(qbase + m*16 + l15)*128 + kc*32 + l4*8);

  f32x4 accO[2][8] = {};
  float mrow[2][4], lrow[2][4];
  #pragma unroll
  for (int m=0;m<2;m++)
    #pragma unroll
    for (int j=0;j<4;j++){ mrow[m][j] = -1e30f; lrow[m][j] = 0.f; }
  const float scale = 0.08838834764831845f;
  const int nsteps = qbase/32 + 1;

  auto LOADK = [&](int kv0, short8 (&kf)[8]){
    #pragma unroll
    for (int n=0;n<2;n++)
      #pragma unroll
      for (int kc=0;kc<4;kc++)
        kf[n*4+kc] = *(const short8*)(Kh + (size_t)(kv0 + n*16 + l15)*128 + kc*32 + l4*8);
  };
  auto LOADV = [&](int kv0, short8 (&vf)[8]){
    #pragma unroll
    for (int db=0;db<8;db++)
      vf[db] = *(const short8*)(Vh + (size_t)(db*16 + l15)*2048 + kv0 + l4*8);
  };
  auto STEP = [&](int s, short8 (&kf)[8], short8 (&vf)[8]){
    const bool diag = (s == nsteps-1);
    f32x4 sc[2][2] = {};
    #pragma unroll
    for (int n=0;n<2;n++)
      #pragma unroll
      for (int m=0;m<2;m++)
        #pragma unroll
        for (int kc=0;kc<4;kc++)
          sc[m][n] = __builtin_amdgcn_mfma_f32_16x16x32_bf16(qf[m][kc], kf[n*4+kc], sc[m][n], 0,0,0);
    float alpha_[2][4];
    #pragma unroll
    for (int m=0;m<2;m++)
      #pragma unroll
      for (int j=0;j<4;j++){
        const int qr = 16*m + 4*l4 + j;
        float a0 = sc[m][0][j]*scale;
        float a1 = sc[m][1][j]*scale;
        if (diag){
          if (l15 > qr)      a0 = -1e30f;
          if (16 + l15 > qr) a1 = -1e30f;
        }
        float mx = fmaxf(a0, a1);
        #pragma unroll
        for (int o=1;o<16;o<<=1) mx = fmaxf(mx, __shfl_xor(mx, o));
        const float mn = fmaxf(mrow[m][j], mx);
        const float p0 = __expf(a0 - mn);
        const float p1 = __expf(a1 - mn);
        float sum = p0 + p1;
        #pragma unroll
        for (int o=1;o<16;o<<=1) sum += __shfl_xor(sum, o);
        const float al = __expf(mrow[m][j] - mn);
        lrow[m][j] = lrow[m][j]*al + sum;
        mrow[m][j] = mn;
        alpha_[m][j] = al;
        pl[qr][l15]    = f2bf(p0);
        pl[qr][16+l15] = f2bf(p1);
      }
    #pragma unroll
    for (int m=0;m<2;m++)
      #pragma unroll
      for (int db=0;db<8;db++)
        #pragma unroll
        for (int j=0;j<4;j++)
          accO[m][db][j] *= alpha_[m][j];
    asm volatile("s_waitcnt lgkmcnt(0)" ::: "memory");
    __builtin_amdgcn_sched_barrier(0);
    short8 pa[2];
    #pragma unroll
    for (int m=0;m<2;m++)
      pa[m] = *(const short8*)(&pl[m*16 + l15][l4*8]);
    #pragma unroll
    for (int db=0;db<8;db++)
      #pragma unroll
      for (int m=0;m<2;m++)
        accO[m][db] = __builtin_amdgcn_mfma_f32_16x16x32_bf16(pa[m], vf[db], accO[m][db], 0,0,0);
  };

  short8 kA[8], kB[8], vf[8];
  LOADK(0, kA);
  int s = 0;
  while (true){
    LOADV(s*32, vf);
    if (s+1 < nsteps) LOADK((s+1)*32, kB);
    STEP(s, kA, vf);
    if (++s >= nsteps) break;
    LOADV(s*32, vf);
    if (s+1 < nsteps) LOADK((s+1)*32, kA);
    STEP(s, kB, vf);
    if (++s >= nsteps) break;
  }

  #pragma unroll
  for (int m=0;m<2;m++)
    #pragma unroll
    for (int db=0;db<8;db++)
      #pragma unroll
      for (int j=0;j<4;j++){
        const int tg = qbase + 16*m + 4*l4 + j;
        const int d  = 16*db + l15;
        Y[((size_t)b*2048 + tg)*2048 + h*128 + d] = f2bf(accO[m][db][j] / lrow[m][j]);
      }
}

// ---------------- launcher ----------------
extern "C" void kernel_launch(void* const* d_in, const int* in_sizes, int n_in,
                              void* d_out, int out_size, void* d_ws, size_t ws_size,
                              hipStream_t stream)
{
  const float* x    = (const float*)d_in[0];
  const float* cosT = (const float*)d_in[1];
  const float* sinT = (const float*)d_in[2];
  const float* ln1w = (const float*)d_in[3];
  const float* ln1b = (const float*)d_in[4];
  const float* ln2w = (const float*)d_in[5];
  const float* ln2b = (const float*)d_in[6];
  const float* Wqkv = (const float*)d_in[7];
  const float* Wo   = (const float*)d_in[8];
  const float* W1   = (const float*)d_in[9];
  const float* W2   = (const float*)d_in[10];
  const float* W3   = (const float*)d_in[11];
  float* out = (float*)d_out;

  if (ws_size < 150994944) return;   // diagnostic: absmax==7.625 -> ws too small
  char* ws = (char*)d_ws;
  __hip_bfloat16* WT   = (__hip_bfloat16*)(ws);                  // [0,32M)
  __hip_bfloat16* abf  = (__hip_bfloat16*)(ws + 33554432);       // [32M,48M)
  __hip_bfloat16* qkvb = (__hip_bfloat16*)(ws + 50331648);       // [48M,96M)
  __hip_bfloat16* Yb   = (__hip_bfloat16*)(ws + 50331648);
  __hip_bfloat16* sub  = (__hip_bfloat16*)(ws + 50331648);       // [48M,112M) after attn
  __hip_bfloat16* Qb   = (__hip_bfloat16*)(ws + 100663296);
  __hip_bfloat16* Kb   = (__hip_bfloat16*)(ws + 117440512);
  __hip_bfloat16* Vtb  = (__hip_bfloat16*)(ws + 134217728);
  float*          x2   = out;

  hipFuncSetAttribute(reinterpret_cast<const void*>(&gemm256<4,256>),
                      hipFuncAttributeMaxDynamicSharedMemorySize, 131072);
  hipFuncSetAttribute(reinterpret_cast<const void*>(&gemm256<2,256>),
                      hipFuncAttributeMaxDynamicSharedMemorySize, 131072);
  hipFuncSetAttribute(reinterpret_cast<const void*>(&gemm256<3,256>),
                      hipFuncAttributeMaxDynamicSharedMemorySize, 131072);
  hipFuncSetAttribute(reinterpret_cast<const void*>(&gemm256<1,128>),
                      hipFuncAttributeMaxDynamicSharedMemorySize, 98304);

  ln_k<<<4096,256,0,stream>>>(x, ln1w, ln1b, abf);
  wtrans<<<dim3(192,64),256,0,stream>>>(Wqkv, WT, 2048, 6144);
  gemm256<4,256><<<384,512,131072,stream>>>(abf, WT, qkvb, nullptr, nullptr, nullptr, 4096, 6144, 2048, 24);
  ropepack<<<dim3(32,32),256,0,stream>>>(qkvb, cosT, sinT, Qb, Kb, Vtb);
  attn_k<<<dim3(16,32),256,0,stream>>>(Qb, Kb, Vtb, Yb);
  wtrans<<<dim3(64,64),256,0,stream>>>(Wo, WT, 2048, 2048);
  gemm256<1,128><<<256,512,98304,stream>>>(Yb, WT, nullptr, x2, x, nullptr, 4096, 2048, 2048, 8);
  ln_k<<<4096,256,0,stream>>>(x2, ln2w, ln2b, abf);
  wtrans<<<dim3(256,64),256,0,stream>>>(W1, WT, 2048, 8192);
  gemm256<2,256><<<512,512,131072,stream>>>(abf, WT, sub, nullptr, nullptr, nullptr, 4096, 8192, 2048, 32);
  wtrans<<<dim3(256,64),256,0,stream>>>(W2, WT, 2048, 8192);
  gemm256<3,256><<<512,512,131072,stream>>>(abf, WT, sub, nullptr, nullptr, sub, 4096, 8192, 2048, 32);
  wtrans<<<dim3(64,256),256,0,stream>>>(W3, WT, 8192, 2048);
  gemm256<1,128><<<256,512,98304,stream>>>(sub, WT, nullptr, out, x2, nullptr, 4096, 2048, 8192, 8);
}

// Round 6
// 871.031 us; speedup vs baseline: 1.2762x; 1.2762x over previous
//
#include <hip/hip_runtime.h>
#include <hip/hip_bf16.h>
#include <cstdint>

#define DEVINL __device__ __forceinline__

using f32x4  = __attribute__((ext_vector_type(4))) float;
using short8 = __attribute__((ext_vector_type(8))) short;
using short4v = __attribute__((ext_vector_type(4))) short;

DEVINL float bf2f(__hip_bfloat16 h){ return __bfloat162float(h); }
DEVINL __hip_bfloat16 f2bf(float f){ return __float2bfloat16(f); }
DEVINL short bfbits(float f){ __hip_bfloat16 h = __float2bfloat16(f); short s; __builtin_memcpy(&s, &h, 2); return s; }
DEVINL float sb2f(short s){ uint32_t u = ((uint32_t)(uint16_t)s) << 16; float f; __builtin_memcpy(&f, &u, 4); return f; }

DEVINL void gl_lds16(const void* g, void* l){
  __builtin_amdgcn_global_load_lds((const __attribute__((address_space(1))) void*)g,
                                   (__attribute__((address_space(3))) void*)l, 16, 0, 0);
}

// ---------------- weight transpose + f32->bf16 cast: dst[C][R] = src[R][C] ----------------
__global__ __launch_bounds__(256) void wtrans(const float* __restrict__ src,
                                              __hip_bfloat16* __restrict__ dst,
                                              int R, int C){
  __shared__ float tile[32][33];
  const int tr0 = blockIdx.y*32, tc0 = blockIdx.x*32;
  const int t = threadIdx.x;
  const int lr = t >> 3, lc = (t & 7) * 4;
  float4 v = *(const float4*)(src + (size_t)(tr0+lr)*C + tc0 + lc);
  tile[lr][lc] = v.x; tile[lr][lc+1] = v.y; tile[lr][lc+2] = v.z; tile[lr][lc+3] = v.w;
  __syncthreads();
  short4v o;
  o[0] = bfbits(tile[lc+0][lr]);
  o[1] = bfbits(tile[lc+1][lr]);
  o[2] = bfbits(tile[lc+2][lr]);
  o[3] = bfbits(tile[lc+3][lr]);
  *(short4v*)(dst + (size_t)(tc0+lr)*R + tr0 + lc) = o;
}

// ---------------- LayerNorm (C=2048), one row per block, bf16 out ----------------
__global__ __launch_bounds__(256) void ln_k(const float* __restrict__ x,
                                            const float* __restrict__ w,
                                            const float* __restrict__ bia,
                                            __hip_bfloat16* __restrict__ out){
  const int row = blockIdx.x, t = threadIdx.x;
  const float* xr = x + (size_t)row*2048;
  float4 v0 = *(const float4*)(xr + t*4);
  float4 v1 = *(const float4*)(xr + 1024 + t*4);
  float s  = v0.x+v0.y+v0.z+v0.w + v1.x+v1.y+v1.z+v1.w;
  float ss = v0.x*v0.x+v0.y*v0.y+v0.z*v0.z+v0.w*v0.w
           + v1.x*v1.x+v1.y*v1.y+v1.z*v1.z+v1.w*v1.w;
  #pragma unroll
  for (int o=1;o<64;o<<=1){ s += __shfl_xor(s,o); ss += __shfl_xor(ss,o); }
  __shared__ float red[8];
  const int wv = t>>6, ln = t&63;
  if (ln==0){ red[wv]=s; red[4+wv]=ss; }
  __syncthreads();
  s = red[0]+red[1]+red[2]+red[3]; ss = red[4]+red[5]+red[6]+red[7];
  const float mu = s*(1.f/2048.f);
  const float inv = rsqrtf(ss*(1.f/2048.f) - mu*mu + 1e-5f);
  {
    float4 wv4 = *(const float4*)(w + t*4);
    float4 bv4 = *(const float4*)(bia + t*4);
    short4v o;
    o[0]=bfbits((v0.x-mu)*inv*wv4.x + bv4.x);
    o[1]=bfbits((v0.y-mu)*inv*wv4.y + bv4.y);
    o[2]=bfbits((v0.z-mu)*inv*wv4.z + bv4.z);
    o[3]=bfbits((v0.w-mu)*inv*wv4.w + bv4.w);
    *(short4v*)(out + (size_t)row*2048 + t*4) = o;
  }
  {
    float4 wv4 = *(const float4*)(w + 1024 + t*4);
    float4 bv4 = *(const float4*)(bia + 1024 + t*4);
    short4v o;
    o[0]=bfbits((v1.x-mu)*inv*wv4.x + bv4.x);
    o[1]=bfbits((v1.y-mu)*inv*wv4.y + bv4.y);
    o[2]=bfbits((v1.z-mu)*inv*wv4.z + bv4.z);
    o[3]=bfbits((v1.w-mu)*inv*wv4.w + bv4.w);
    *(short4v*)(out + (size_t)row*2048 + 1024 + t*4) = o;
  }
}

// ======== deep-pipelined GEMM: C[M,N] = A[M,K]*Bt[N,K]^T, tile BM x 256, BK=64 ========
template<int EPI, int BM>
__global__ __launch_bounds__(512, 2) void gemm256(
    const __hip_bfloat16* __restrict__ A,
    const __hip_bfloat16* __restrict__ Bt,
    __hip_bfloat16* __restrict__ Cb,
    float* __restrict__ Cf,
    const float* __restrict__ resid,
    const __hip_bfloat16* __restrict__ emul,
    int M, int N, int K, int NTN)
{
  constexpr int MF     = BM/32;
  constexpr int NA     = BM/64;
  constexpr int ABYTES = BM*128;
  constexpr int TILEB  = ABYTES + 32768;
  constexpr int NLD    = NA + 4;
  extern __shared__ char smem[];
  const int tid = threadIdx.x, lane = tid & 63, wave = tid >> 6;
  const int l15 = lane & 15, l4 = lane >> 4;
  const int wm = wave >> 2, wn = wave & 3;

  const int nwg = gridDim.x;
  const int id  = blockIdx.x;
  const int swz = (id & 7) * (nwg >> 3) + (id >> 3);
  const int by = swz / NTN, bx = swz % NTN;
  const int row0 = by * BM, col0 = bx * 256;

  const __hip_bfloat16* gptr[NLD];
  int ldsoff[NLD];
  #pragma unroll
  for (int g = 0; g < NLD; ++g){
    const int gg = (g < NA) ? g : g - NA;
    const int r    = gg*64 + (tid >> 3);
    const int colp = (tid & 7) * 16;
    const int coll = colp ^ ((r & 7) << 4);
    if (g < NA) gptr[g] = A  + (size_t)(row0 + r)*K + (coll >> 1);
    else        gptr[g] = Bt + (size_t)(col0 + r)*K + (coll >> 1);
    ldsoff[g] = (g < NA ? 0 : ABYTES) + gg*8192 + tid*16;
  }
  auto STAGE = [&](int bufc, int ktile){
    #pragma unroll
    for (int g = 0; g < NLD; ++g)
      gl_lds16(gptr[g] + (size_t)ktile*64, smem + bufc + ldsoff[g]);
  };

  const int swzm = (l15 & 7) << 4;
  const int aRow = (wm*(BM/2) + l15) * 128;
  const int bRow = ABYTES + (wn*64 + l15) * 128;
  const int colT0 = (l4*16) ^ swzm;
  const int colT1 = (64 + l4*16) ^ swzm;

  f32x4 acc[MF][4] = {};
  const int NT = K >> 6;

  STAGE(0, 0);
  STAGE(TILEB, 1);
  __builtin_amdgcn_sched_barrier(0);
  if constexpr (BM == 256) asm volatile("s_waitcnt vmcnt(8)" ::: "memory");
  else                     asm volatile("s_waitcnt vmcnt(6)" ::: "memory");
  __builtin_amdgcn_s_barrier();
  __builtin_amdgcn_sched_barrier(0);

  for (int t = 0; t < NT; ++t){
    const int bufc = (t & 1) * TILEB;
    #pragma unroll
    for (int ks = 0; ks < 2; ++ks){
      const int ct = (ks == 0) ? colT0 : colT1;
      short8 a[MF], b[4];
      #pragma unroll
      for (int m = 0; m < MF; ++m) a[m] = *(const short8*)(smem + bufc + aRow + m*2048 + ct);
      #pragma unroll
      for (int n = 0; n < 4; ++n) b[n] = *(const short8*)(smem + bufc + bRow + n*2048 + ct);
      __builtin_amdgcn_s_setprio(1);
      #pragma unroll
      for (int m = 0; m < MF; ++m)
        #pragma unroll
        for (int n = 0; n < 4; ++n)
          acc[m][n] = __builtin_amdgcn_mfma_f32_16x16x32_bf16(a[m], b[n], acc[m][n], 0, 0, 0);
      __builtin_amdgcn_s_setprio(0);
    }
    __builtin_amdgcn_sched_barrier(0);
    __builtin_amdgcn_s_barrier();
    __builtin_amdgcn_sched_barrier(0);
    if (t + 2 < NT){
      STAGE(bufc, t + 2);
      __builtin_amdgcn_sched_barrier(0);
      if constexpr (BM == 256) asm volatile("s_waitcnt vmcnt(8)" ::: "memory");
      else                     asm volatile("s_waitcnt vmcnt(6)" ::: "memory");
    } else {
      asm volatile("s_waitcnt vmcnt(0)" ::: "memory");
    }
    __builtin_amdgcn_s_barrier();
    __builtin_amdgcn_sched_barrier(0);
  }

  #pragma unroll
  for (int m = 0; m < MF; ++m){
    const int r0 = row0 + wm*(BM/2) + m*16 + l4*4;
    #pragma unroll
    for (int n = 0; n < 4; ++n){
      const int c = col0 + wn*64 + n*16 + l15;
      #pragma unroll
      for (int j = 0; j < 4; ++j){
        const size_t idx = (size_t)(r0 + j)*N + c;
        const float v = acc[m][n][j];
        if constexpr (EPI == 1)      Cf[idx] = v + resid[idx];
        else if constexpr (EPI == 2) Cb[idx] = f2bf(v / (1.f + __expf(-v)));
        else if constexpr (EPI == 3) Cb[idx] = f2bf(v * bf2f(emul[idx]));
        else                         Cb[idx] = f2bf(v);
      }
    }
  }
}

// ------ RoPE + pack: qkv bf16 (B,T,3C) -> Q,K (BH,T,128) bf16, Vt (BH,128,T) bf16 ------
__global__ __launch_bounds__(256) void ropepack(
    const __hip_bfloat16* __restrict__ qkv, const float* __restrict__ cosT, const float* __restrict__ sinT,
    __hip_bfloat16* __restrict__ Qo, __hip_bfloat16* __restrict__ Ko, __hip_bfloat16* __restrict__ Vo)
{
  __shared__ short vt[128][72];
  const int bh = blockIdx.y, b = bh>>4, h = bh&15;
  const int t0 = blockIdx.x*64, tid = threadIdx.x;
  const int tr = tid>>2, q4 = tid&3;
  const int tg = t0 + tr;
  const __hip_bfloat16* base = qkv + ((size_t)(b*2048 + tg))*6144 + h*128;
  const int pp0 = q4*16;
  float cs[16], sn[16];
  #pragma unroll
  for (int i=0;i<4;i++){
    float4 c4 = *(const float4*)(cosT + (size_t)tg*64 + pp0 + i*4);
    float4 s4 = *(const float4*)(sinT + (size_t)tg*64 + pp0 + i*4);
    cs[i*4+0]=c4.x; cs[i*4+1]=c4.y; cs[i*4+2]=c4.z; cs[i*4+3]=c4.w;
    sn[i*4+0]=s4.x; sn[i*4+1]=s4.y; sn[i*4+2]=s4.z; sn[i*4+3]=s4.w;
  }
  #pragma unroll
  for (int qk=0; qk<2; ++qk){
    const __hip_bfloat16* src = base + qk*2048;
    __hip_bfloat16* dst = (qk==0 ? Qo : Ko) + ((size_t)bh*2048 + tg)*128 + pp0*2;
    short8 ov[4];
    short* o = (short*)ov;
    #pragma unroll
    for (int i=0;i<4;i++){
      short8 v = *(const short8*)(src + pp0*2 + i*8);
      #pragma unroll
      for (int j=0;j<4;j++){
        float xe = sb2f(v[2*j]), xo = sb2f(v[2*j+1]);
        float c = cs[4*i+j], s = sn[4*i+j];
        o[8*i+2*j]   = bfbits(xe*c - xo*s);
        o[8*i+2*j+1] = bfbits(xe*s + xo*c);
      }
    }
    #pragma unroll
    for (int i=0;i<4;i++) *(short8*)(dst + i*8) = ov[i];
  }
  const __hip_bfloat16* vsrc = base + 4096;
  const int vc0 = q4*32;
  #pragma unroll
  for (int i=0;i<4;i++){
    short8 v = *(const short8*)(vsrc + vc0 + i*8);
    #pragma unroll
    for (int j=0;j<8;j++) vt[vc0+i*8+j][tr] = v[j];
  }
  __syncthreads();
  const int d = tid>>1, th0 = (tid&1)*32;
  __hip_bfloat16* vdst = Vo + ((size_t)bh*128 + d)*2048 + t0 + th0;
  #pragma unroll
  for (int i=0;i<4;i++)
    *(short8*)(vdst + i*8) = *(const short8*)(&vt[d][th0 + i*8]);
}

// ----- Flash attention, causal: cooperative LDS K/V pipeline, 4 waves x 32 q-rows -----
__global__ __launch_bounds__(256) void attn_k(
    const __hip_bfloat16* __restrict__ Q,
    const __hip_bfloat16* __restrict__ K,
    const __hip_bfloat16* __restrict__ Vt,
    __hip_bfloat16* __restrict__ Y)
{
  // LDS: K dbuf @0 (2x8KB), V dbuf @16384 (2x8KB), P @32768 (4x32x40x2B)
  __shared__ char lds[43008];
  const int bh = blockIdx.x, b = bh>>4, h = bh&15;
  const int by = blockIdx.y;
  const int qt = (by < 8) ? (15 - 2*by) : (2*(by - 8));
  const int tid = threadIdx.x, lane = tid&63, wave = tid>>6;
  const int qbase = qt*128 + wave*32;
  const int nsteps = qt*4 + 4;                      // block-uniform trip count
  const __hip_bfloat16* Qh = Q + (size_t)bh*2048*128;
  const __hip_bfloat16* Kh = K + (size_t)bh*2048*128;
  const __hip_bfloat16* Vh = Vt + (size_t)bh*128*2048;
  __hip_bfloat16 (*pl)[40] = ((__hip_bfloat16 (*)[40])(lds + 32768)) + wave*32;
  const int l15 = lane & 15, l4 = lane >> 4;

  // staging source offsets (K pre-swizzled so LDS-linear dest + XOR read round-trips)
  const int kr0 = tid >> 4, kj = tid & 15;
  const size_t ksrc0 = (size_t)kr0*128 + (((kj*16) ^ ((kr0 & 7) << 4)) >> 1);
  const int kr1 = kr0 + 16;
  const size_t ksrc1 = (size_t)kr1*128 + (((kj*16) ^ ((kr1 & 7) << 4)) >> 1);
  const int vd0 = tid >> 2, vj = tid & 3;
  const size_t vsrc0 = (size_t)vd0*2048 + vj*8;
  const size_t vsrc1 = (size_t)(vd0 + 64)*2048 + vj*8;
  auto STAGE = [&](int buf, int kv0){
    char* kb = lds + buf*8192 + tid*16;
    char* vb = lds + 16384 + buf*8192 + tid*16;
    gl_lds16(Kh + (size_t)kv0*128 + ksrc0, kb);
    gl_lds16(Kh + (size_t)kv0*128 + ksrc1, kb + 4096);
    gl_lds16(Vh + kv0 + vsrc0, vb);
    gl_lds16(Vh + kv0 + vsrc1, vb + 4096);
  };

  short8 qf[2][4];
  #pragma unroll
  for (int m=0;m<2;m++)
    #pragma unroll
    for (int kc=0;kc<4;kc++)
      qf[m][kc] = *(const short8*)(Qh + (size_t)(qbase + m*16 + l15)*128 + kc*32 + l4*8);

  f32x4 accO[2][8] = {};
  float mrow[2][4], lrow[2][4];
  #pragma unroll
  for (int m=0;m<2;m++)
    #pragma unroll
    for (int j=0;j<4;j++){ mrow[m][j] = -1e30f; lrow[m][j] = 0.f; }
  const float scale = 0.08838834764831845f;

  STAGE(0, 0);
  STAGE(1, 32);
  __builtin_amdgcn_sched_barrier(0);
  asm volatile("s_waitcnt vmcnt(4)" ::: "memory");
  __builtin_amdgcn_s_barrier();
  __builtin_amdgcn_sched_barrier(0);

  for (int s = 0; s < nsteps; ++s){
    const int kv0 = s*32;
    const char* kb = lds + (s&1)*8192;
    const char* vb = lds + 16384 + (s&1)*8192;
    if (kv0 <= qbase){
      const bool diag = (kv0 == qbase);
      short8 kf[8];
      #pragma unroll
      for (int n=0;n<2;n++)
        #pragma unroll
        for (int kc=0;kc<4;kc++)
          kf[n*4+kc] = *(const short8*)(kb + (n*16 + l15)*256 + ((kc*64 + l4*16) ^ ((l15 & 7) << 4)));
      f32x4 sc[2][2] = {};
      #pragma unroll
      for (int n=0;n<2;n++)
        #pragma unroll
        for (int m=0;m<2;m++)
          #pragma unroll
          for (int kc=0;kc<4;kc++)
            sc[m][n] = __builtin_amdgcn_mfma_f32_16x16x32_bf16(qf[m][kc], kf[n*4+kc], sc[m][n], 0,0,0);
      float alpha_[2][4];
      #pragma unroll
      for (int m=0;m<2;m++)
        #pragma unroll
        for (int j=0;j<4;j++){
          const int qr = 16*m + 4*l4 + j;
          float a0 = sc[m][0][j]*scale;
          float a1 = sc[m][1][j]*scale;
          if (diag){
            if (l15 > qr)      a0 = -1e30f;
            if (16 + l15 > qr) a1 = -1e30f;
          }
          float mx = fmaxf(a0, a1);
          #pragma unroll
          for (int o=1;o<16;o<<=1) mx = fmaxf(mx, __shfl_xor(mx, o));
          const float mn = fmaxf(mrow[m][j], mx);
          const float p0 = __expf(a0 - mn);
          const float p1 = __expf(a1 - mn);
          float sum = p0 + p1;
          #pragma unroll
          for (int o=1;o<16;o<<=1) sum += __shfl_xor(sum, o);
          const float al = __expf(mrow[m][j] - mn);
          lrow[m][j] = lrow[m][j]*al + sum;
          mrow[m][j] = mn;
          alpha_[m][j] = al;
          pl[qr][l15]    = f2bf(p0);
          pl[qr][16+l15] = f2bf(p1);
        }
      #pragma unroll
      for (int m=0;m<2;m++)
        #pragma unroll
        for (int db=0;db<8;db++)
          #pragma unroll
          for (int j=0;j<4;j++)
            accO[m][db][j] *= alpha_[m][j];
      asm volatile("s_waitcnt lgkmcnt(0)" ::: "memory");
      __builtin_amdgcn_sched_barrier(0);
      short8 pa[2];
      #pragma unroll
      for (int m=0;m<2;m++)
        pa[m] = *(const short8*)(&pl[m*16 + l15][l4*8]);
      short8 vf[8];
      #pragma unroll
      for (int db=0;db<8;db++)
        vf[db] = *(const short8*)(vb + (db*16 + l15)*64 + l4*16);
      #pragma unroll
      for (int db=0;db<8;db++)
        #pragma unroll
        for (int m=0;m<2;m++)
          accO[m][db] = __builtin_amdgcn_mfma_f32_16x16x32_bf16(pa[m], vf[db], accO[m][db], 0,0,0);
    }
    __builtin_amdgcn_sched_barrier(0);
    __builtin_amdgcn_s_barrier();              // all waves done reading buf[s&1]
    __builtin_amdgcn_sched_barrier(0);
    if (s + 2 < nsteps){
      STAGE(s&1, (s+2)*32);
      __builtin_amdgcn_sched_barrier(0);
      asm volatile("s_waitcnt vmcnt(4)" ::: "memory");   // tile s+1 resident
    } else {
      asm volatile("s_waitcnt vmcnt(0)" ::: "memory");
    }
    __builtin_amdgcn_s_barrier();
    __builtin_amdgcn_sched_barrier(0);
  }

  #pragma unroll
  for (int m=0;m<2;m++)
    #pragma unroll
    for (int db=0;db<8;db++)
      #pragma unroll
      for (int j=0;j<4;j++){
        const int tg = qbase + 16*m + 4*l4 + j;
        const int d  = 16*db + l15;
        Y[((size_t)b*2048 + tg)*2048 + h*128 + d] = f2bf(accO[m][db][j] / lrow[m][j]);
      }
}

// ---------------- launcher ----------------
extern "C" void kernel_launch(void* const* d_in, const int* in_sizes, int n_in,
                              void* d_out, int out_size, void* d_ws, size_t ws_size,
                              hipStream_t stream)
{
  const float* x    = (const float*)d_in[0];
  const float* cosT = (const float*)d_in[1];
  const float* sinT = (const float*)d_in[2];
  const float* ln1w = (const float*)d_in[3];
  const float* ln1b = (const float*)d_in[4];
  const float* ln2w = (const float*)d_in[5];
  const float* ln2b = (const float*)d_in[6];
  const float* Wqkv = (const float*)d_in[7];
  const float* Wo   = (const float*)d_in[8];
  const float* W1   = (const float*)d_in[9];
  const float* W2   = (const float*)d_in[10];
  const float* W3   = (const float*)d_in[11];
  float* out = (float*)d_out;

  if (ws_size < 150994944) return;   // diagnostic: absmax==7.625 -> ws too small
  char* ws = (char*)d_ws;
  __hip_bfloat16* WT   = (__hip_bfloat16*)(ws);                  // [0,32M)
  __hip_bfloat16* abf  = (__hip_bfloat16*)(ws + 33554432);       // [32M,48M)
  __hip_bfloat16* qkvb = (__hip_bfloat16*)(ws + 50331648);       // [48M,96M)
  __hip_bfloat16* Yb   = (__hip_bfloat16*)(ws + 50331648);
  __hip_bfloat16* sub  = (__hip_bfloat16*)(ws + 50331648);       // [48M,112M) after attn
  __hip_bfloat16* Qb   = (__hip_bfloat16*)(ws + 100663296);
  __hip_bfloat16* Kb   = (__hip_bfloat16*)(ws + 117440512);
  __hip_bfloat16* Vtb  = (__hip_bfloat16*)(ws + 134217728);
  float*          x2   = out;

  hipFuncSetAttribute(reinterpret_cast<const void*>(&gemm256<4,256>),
                      hipFuncAttributeMaxDynamicSharedMemorySize, 131072);
  hipFuncSetAttribute(reinterpret_cast<const void*>(&gemm256<2,256>),
                      hipFuncAttributeMaxDynamicSharedMemorySize, 131072);
  hipFuncSetAttribute(reinterpret_cast<const void*>(&gemm256<3,256>),
                      hipFuncAttributeMaxDynamicSharedMemorySize, 131072);
  hipFuncSetAttribute(reinterpret_cast<const void*>(&gemm256<1,128>),
                      hipFuncAttributeMaxDynamicSharedMemorySize, 98304);

  ln_k<<<4096,256,0,stream>>>(x, ln1w, ln1b, abf);
  wtrans<<<dim3(192,64),256,0,stream>>>(Wqkv, WT, 2048, 6144);
  gemm256<4,256><<<384,512,131072,stream>>>(abf, WT, qkvb, nullptr, nullptr, nullptr, 4096, 6144, 2048, 24);
  ropepack<<<dim3(32,32),256,0,stream>>>(qkvb, cosT, sinT, Qb, Kb, Vtb);
  attn_k<<<dim3(32,16),256,0,stream>>>(Qb, Kb, Vtb, Yb);
  wtrans<<<dim3(64,64),256,0,stream>>>(Wo, WT, 2048, 2048);
  gemm256<1,128><<<256,512,98304,stream>>>(Yb, WT, nullptr, x2, x, nullptr, 4096, 2048, 2048, 8);
  ln_k<<<4096,256,0,stream>>>(x2, ln2w, ln2b, abf);
  wtrans<<<dim3(256,64),256,0,stream>>>(W1, WT, 2048, 8192);
  gemm256<2,256><<<512,512,131072,stream>>>(abf, WT, sub, nullptr, nullptr, nullptr, 4096, 8192, 2048, 32);
  wtrans<<<dim3(256,64),256,0,stream>>>(W2, WT, 2048, 8192);
  gemm256<3,256><<<512,512,131072,stream>>>(abf, WT, sub, nullptr, nullptr, sub, 4096, 8192, 2048, 32);
  wtrans<<<dim3(64,256),256,0,stream>>>(W3, WT, 8192, 2048);
  gemm256<1,128><<<256,512,98304,stream>>>(sub, WT, nullptr, out, x2, nullptr, 4096, 2048, 8192, 8);
}

// Round 7
// 813.328 us; speedup vs baseline: 1.3668x; 1.0709x over previous
//
#include <hip/hip_runtime.h>
#include <hip/hip_bf16.h>
#include <cstdint>

#define DEVINL __device__ __forceinline__

using f32x4  = __attribute__((ext_vector_type(4))) float;
using short8 = __attribute__((ext_vector_type(8))) short;
using short4v = __attribute__((ext_vector_type(4))) short;

DEVINL float bf2f(__hip_bfloat16 h){ return __bfloat162float(h); }
DEVINL __hip_bfloat16 f2bf(float f){ return __float2bfloat16(f); }
DEVINL short bfbits(float f){ __hip_bfloat16 h = __float2bfloat16(f); short s; __builtin_memcpy(&s, &h, 2); return s; }
DEVINL float sb2f(short s){ uint32_t u = ((uint32_t)(uint16_t)s) << 16; float f; __builtin_memcpy(&f, &u, 4); return f; }

DEVINL void gl_lds16(const void* g, void* l){
  __builtin_amdgcn_global_load_lds((const __attribute__((address_space(1))) void*)g,
                                   (__attribute__((address_space(3))) void*)l, 16, 0, 0);
}

// ---------------- weight transpose + f32->bf16 cast: dst[C][R] = src[R][C] ----------------
__global__ __launch_bounds__(256) void wtrans(const float* __restrict__ src,
                                              __hip_bfloat16* __restrict__ dst,
                                              int R, int C){
  __shared__ float tile[32][33];
  const int tr0 = blockIdx.y*32, tc0 = blockIdx.x*32;
  const int t = threadIdx.x;
  const int lr = t >> 3, lc = (t & 7) * 4;
  float4 v = *(const float4*)(src + (size_t)(tr0+lr)*C + tc0 + lc);
  tile[lr][lc] = v.x; tile[lr][lc+1] = v.y; tile[lr][lc+2] = v.z; tile[lr][lc+3] = v.w;
  __syncthreads();
  short4v o;
  o[0] = bfbits(tile[lc+0][lr]);
  o[1] = bfbits(tile[lc+1][lr]);
  o[2] = bfbits(tile[lc+2][lr]);
  o[3] = bfbits(tile[lc+3][lr]);
  *(short4v*)(dst + (size_t)(tc0+lr)*R + tr0 + lc) = o;
}

// ---------------- LayerNorm (C=2048), one row per block, bf16 out ----------------
__global__ __launch_bounds__(256) void ln_k(const float* __restrict__ x,
                                            const float* __restrict__ w,
                                            const float* __restrict__ bia,
                                            __hip_bfloat16* __restrict__ out){
  const int row = blockIdx.x, t = threadIdx.x;
  const float* xr = x + (size_t)row*2048;
  float4 v0 = *(const float4*)(xr + t*4);
  float4 v1 = *(const float4*)(xr + 1024 + t*4);
  float s  = v0.x+v0.y+v0.z+v0.w + v1.x+v1.y+v1.z+v1.w;
  float ss = v0.x*v0.x+v0.y*v0.y+v0.z*v0.z+v0.w*v0.w
           + v1.x*v1.x+v1.y*v1.y+v1.z*v1.z+v1.w*v1.w;
  #pragma unroll
  for (int o=1;o<64;o<<=1){ s += __shfl_xor(s,o); ss += __shfl_xor(ss,o); }
  __shared__ float red[8];
  const int wv = t>>6, ln = t&63;
  if (ln==0){ red[wv]=s; red[4+wv]=ss; }
  __syncthreads();
  s = red[0]+red[1]+red[2]+red[3]; ss = red[4]+red[5]+red[6]+red[7];
  const float mu = s*(1.f/2048.f);
  const float inv = rsqrtf(ss*(1.f/2048.f) - mu*mu + 1e-5f);
  {
    float4 wv4 = *(const float4*)(w + t*4);
    float4 bv4 = *(const float4*)(bia + t*4);
    short4v o;
    o[0]=bfbits((v0.x-mu)*inv*wv4.x + bv4.x);
    o[1]=bfbits((v0.y-mu)*inv*wv4.y + bv4.y);
    o[2]=bfbits((v0.z-mu)*inv*wv4.z + bv4.z);
    o[3]=bfbits((v0.w-mu)*inv*wv4.w + bv4.w);
    *(short4v*)(out + (size_t)row*2048 + t*4) = o;
  }
  {
    float4 wv4 = *(const float4*)(w + 1024 + t*4);
    float4 bv4 = *(const float4*)(bia + 1024 + t*4);
    short4v o;
    o[0]=bfbits((v1.x-mu)*inv*wv4.x + bv4.x);
    o[1]=bfbits((v1.y-mu)*inv*wv4.y + bv4.y);
    o[2]=bfbits((v1.z-mu)*inv*wv4.z + bv4.z);
    o[3]=bfbits((v1.w-mu)*inv*wv4.w + bv4.w);
    *(short4v*)(out + (size_t)row*2048 + 1024 + t*4) = o;
  }
}

// ======== deep-pipelined GEMM: C[M,N] = A[M,K]*Bt[N,K]^T, tile BM x 256, BK=64 ========
template<int EPI, int BM>
__global__ __launch_bounds__(512, 2) void gemm256(
    const __hip_bfloat16* __restrict__ A,
    const __hip_bfloat16* __restrict__ Bt,
    __hip_bfloat16* __restrict__ Cb,
    float* __restrict__ Cf,
    const float* __restrict__ resid,
    const __hip_bfloat16* __restrict__ emul,
    int M, int N, int K, int NTN)
{
  constexpr int MF     = BM/32;
  constexpr int NA     = BM/64;
  constexpr int ABYTES = BM*128;
  constexpr int TILEB  = ABYTES + 32768;
  constexpr int NLD    = NA + 4;
  extern __shared__ char smem[];
  const int tid = threadIdx.x, lane = tid & 63, wave = tid >> 6;
  const int l15 = lane & 15, l4 = lane >> 4;
  const int wm = wave >> 2, wn = wave & 3;

  const int nwg = gridDim.x;
  const int id  = blockIdx.x;
  const int swz = (id & 7) * (nwg >> 3) + (id >> 3);
  const int by = swz / NTN, bx = swz % NTN;
  const int row0 = by * BM, col0 = bx * 256;

  const __hip_bfloat16* gptr[NLD];
  int ldsoff[NLD];
  #pragma unroll
  for (int g = 0; g < NLD; ++g){
    const int gg = (g < NA) ? g : g - NA;
    const int r    = gg*64 + (tid >> 3);
    const int colp = (tid & 7) * 16;
    const int coll = colp ^ ((r & 7) << 4);
    if (g < NA) gptr[g] = A  + (size_t)(row0 + r)*K + (coll >> 1);
    else        gptr[g] = Bt + (size_t)(col0 + r)*K + (coll >> 1);
    ldsoff[g] = (g < NA ? 0 : ABYTES) + gg*8192 + tid*16;
  }
  auto STAGE = [&](int bufc, int ktile){
    #pragma unroll
    for (int g = 0; g < NLD; ++g)
      gl_lds16(gptr[g] + (size_t)ktile*64, smem + bufc + ldsoff[g]);
  };

  const int swzm = (l15 & 7) << 4;
  const int aRow = (wm*(BM/2) + l15) * 128;
  const int bRow = ABYTES + (wn*64 + l15) * 128;
  const int colT0 = (l4*16) ^ swzm;
  const int colT1 = (64 + l4*16) ^ swzm;

  f32x4 acc[MF][4] = {};
  const int NT = K >> 6;

  STAGE(0, 0);
  STAGE(TILEB, 1);
  __builtin_amdgcn_sched_barrier(0);
  if constexpr (BM == 256) asm volatile("s_waitcnt vmcnt(8)" ::: "memory");
  else                     asm volatile("s_waitcnt vmcnt(6)" ::: "memory");
  __builtin_amdgcn_s_barrier();
  __builtin_amdgcn_sched_barrier(0);

  for (int t = 0; t < NT; ++t){
    const int bufc = (t & 1) * TILEB;
    #pragma unroll
    for (int ks = 0; ks < 2; ++ks){
      const int ct = (ks == 0) ? colT0 : colT1;
      short8 a[MF], b[4];
      #pragma unroll
      for (int m = 0; m < MF; ++m) a[m] = *(const short8*)(smem + bufc + aRow + m*2048 + ct);
      #pragma unroll
      for (int n = 0; n < 4; ++n) b[n] = *(const short8*)(smem + bufc + bRow + n*2048 + ct);
      __builtin_amdgcn_s_setprio(1);
      #pragma unroll
      for (int m = 0; m < MF; ++m)
        #pragma unroll
        for (int n = 0; n < 4; ++n)
          acc[m][n] = __builtin_amdgcn_mfma_f32_16x16x32_bf16(a[m], b[n], acc[m][n], 0, 0, 0);
      __builtin_amdgcn_s_setprio(0);
    }
    __builtin_amdgcn_sched_barrier(0);
    __builtin_amdgcn_s_barrier();
    __builtin_amdgcn_sched_barrier(0);
    if (t + 2 < NT){
      STAGE(bufc, t + 2);
      __builtin_amdgcn_sched_barrier(0);
      if constexpr (BM == 256) asm volatile("s_waitcnt vmcnt(8)" ::: "memory");
      else                     asm volatile("s_waitcnt vmcnt(6)" ::: "memory");
    } else {
      asm volatile("s_waitcnt vmcnt(0)" ::: "memory");
    }
    __builtin_amdgcn_s_barrier();
    __builtin_amdgcn_sched_barrier(0);
  }

  #pragma unroll
  for (int m = 0; m < MF; ++m){
    const int r0 = row0 + wm*(BM/2) + m*16 + l4*4;
    #pragma unroll
    for (int n = 0; n < 4; ++n){
      const int c = col0 + wn*64 + n*16 + l15;
      #pragma unroll
      for (int j = 0; j < 4; ++j){
        const size_t idx = (size_t)(r0 + j)*N + c;
        const float v = acc[m][n][j];
        if constexpr (EPI == 1)      Cf[idx] = v + resid[idx];
        else if constexpr (EPI == 2) Cb[idx] = f2bf(v / (1.f + __expf(-v)));
        else if constexpr (EPI == 3) Cb[idx] = f2bf(v * bf2f(emul[idx]));
        else                         Cb[idx] = f2bf(v);
      }
    }
  }
}

// ------ RoPE + pack: qkv bf16 (B,T,3C) -> Q,K (BH,T,128) bf16, Vt (BH,128,T) bf16 ------
__global__ __launch_bounds__(256) void ropepack(
    const __hip_bfloat16* __restrict__ qkv, const float* __restrict__ cosT, const float* __restrict__ sinT,
    __hip_bfloat16* __restrict__ Qo, __hip_bfloat16* __restrict__ Ko, __hip_bfloat16* __restrict__ Vo)
{
  __shared__ short vt[128][72];
  const int bh = blockIdx.y, b = bh>>4, h = bh&15;
  const int t0 = blockIdx.x*64, tid = threadIdx.x;
  const int tr = tid>>2, q4 = tid&3;
  const int tg = t0 + tr;
  const __hip_bfloat16* base = qkv + ((size_t)(b*2048 + tg))*6144 + h*128;
  const int pp0 = q4*16;
  float cs[16], sn[16];
  #pragma unroll
  for (int i=0;i<4;i++){
    float4 c4 = *(const float4*)(cosT + (size_t)tg*64 + pp0 + i*4);
    float4 s4 = *(const float4*)(sinT + (size_t)tg*64 + pp0 + i*4);
    cs[i*4+0]=c4.x; cs[i*4+1]=c4.y; cs[i*4+2]=c4.z; cs[i*4+3]=c4.w;
    sn[i*4+0]=s4.x; sn[i*4+1]=s4.y; sn[i*4+2]=s4.z; sn[i*4+3]=s4.w;
  }
  #pragma unroll
  for (int qk=0; qk<2; ++qk){
    const __hip_bfloat16* src = base + qk*2048;
    __hip_bfloat16* dst = (qk==0 ? Qo : Ko) + ((size_t)bh*2048 + tg)*128 + pp0*2;
    short8 ov[4];
    short* o = (short*)ov;
    #pragma unroll
    for (int i=0;i<4;i++){
      short8 v = *(const short8*)(src + pp0*2 + i*8);
      #pragma unroll
      for (int j=0;j<4;j++){
        float xe = sb2f(v[2*j]), xo = sb2f(v[2*j+1]);
        float c = cs[4*i+j], s = sn[4*i+j];
        o[8*i+2*j]   = bfbits(xe*c - xo*s);
        o[8*i+2*j+1] = bfbits(xe*s + xo*c);
      }
    }
    #pragma unroll
    for (int i=0;i<4;i++) *(short8*)(dst + i*8) = ov[i];
  }
  const __hip_bfloat16* vsrc = base + 4096;
  const int vc0 = q4*32;
  #pragma unroll
  for (int i=0;i<4;i++){
    short8 v = *(const short8*)(vsrc + vc0 + i*8);
    #pragma unroll
    for (int j=0;j<8;j++) vt[vc0+i*8+j][tr] = v[j];
  }
  __syncthreads();
  const int d = tid>>1, th0 = (tid&1)*32;
  __hip_bfloat16* vdst = Vo + ((size_t)bh*128 + d)*2048 + t0 + th0;
  #pragma unroll
  for (int i=0;i<4;i++)
    *(short8*)(vdst + i*8) = *(const short8*)(&vt[d][th0 + i*8]);
}

// ----- Flash attention, causal: 8 waves, KVBLK=64, LDS dbuf, ones-MFMA denominator -----
// grid (bh=32, by=8): waves 0-3 -> supertile qtA=15-2by, waves 4-7 -> qtB=2by.
// Each block = 132 active wave-steps (uniform). 1 block/CU.
__global__ __launch_bounds__(512, 2) void attn_k(
    const __hip_bfloat16* __restrict__ Q,
    const __hip_bfloat16* __restrict__ K,
    const __hip_bfloat16* __restrict__ Vt,
    __hip_bfloat16* __restrict__ Y)
{
  // dynamic LDS: K dbuf 2x16KB @0, V dbuf 2x16KB @32768, P 8x32x72x2B @65536 (=102400)
  extern __shared__ char lds[];
  const int bh = blockIdx.x, b = bh>>4, h = bh&15;
  const int by = blockIdx.y;
  const int qtA = 15 - 2*by, qtB = 2*by;
  const int tid = threadIdx.x, lane = tid&63, wave = tid>>6;
  const int qt = (wave < 4) ? qtA : qtB;
  const int qbase = qt*128 + (wave&3)*32;
  const int qmax = (qtA > qtB) ? qtA : qtB;
  const int nsteps = 2*qmax + 2;
  const __hip_bfloat16* Qh = Q + (size_t)bh*2048*128;
  const __hip_bfloat16* Kh = K + (size_t)bh*2048*128;
  const __hip_bfloat16* Vh = Vt + (size_t)bh*128*2048;
  char* plbase = lds + 65536 + wave*4608;          // 32 rows x 144 B
  const int l15 = lane & 15, l4 = lane >> 4;
  const int swzm = (l15 & 7) << 4;

  // staging offsets: K tile [64 keys][256B], V tile [128 d][128B]; pre-swizzled source
  const int krA = tid >> 4;  const int kjA = (tid & 15) * 16;
  const size_t ksrcA = (size_t)krA*128 + ((kjA ^ ((krA & 7) << 4)) >> 1);
  const size_t ksrcB = (size_t)(krA+32)*128 + ((kjA ^ ((krA & 7) << 4)) >> 1);
  const int vrA = tid >> 3;  const int vjA = (tid & 7) * 16;
  const size_t vsrcA = (size_t)vrA*2048 + ((vjA ^ ((vrA & 7) << 4)) >> 1);
  const size_t vsrcB = (size_t)(vrA+64)*2048 + ((vjA ^ ((vrA & 7) << 4)) >> 1);
  auto STAGE = [&](int buf, int kv0){
    char* kb = lds + buf*16384;
    char* vb = lds + 32768 + buf*16384;
    gl_lds16(Kh + (size_t)kv0*128 + ksrcA, kb + tid*16);
    gl_lds16(Kh + (size_t)kv0*128 + ksrcB, kb + 8192 + tid*16);
    gl_lds16(Vh + kv0 + vsrcA, vb + tid*16);
    gl_lds16(Vh + kv0 + vsrcB, vb + 8192 + tid*16);
  };

  short8 qf[2][4];
  #pragma unroll
  for (int m=0;m<2;m++)
    #pragma unroll
    for (int kc=0;kc<4;kc++)
      qf[m][kc] = *(const short8*)(Qh + (size_t)(qbase + m*16 + l15)*128 + kc*32 + l4*8);

  short8 of;                                       // ones B-fragment: col 0 = 1.0
  #pragma unroll
  for (int i=0;i<8;i++) of[i] = (l15==0) ? (short)0x3F80 : (short)0;

  f32x4 accO[2][9] = {};
  float mrow[2][4];
  #pragma unroll
  for (int m=0;m<2;m++)
    #pragma unroll
    for (int j=0;j<4;j++) mrow[m][j] = -1e30f;
  const float scale = 0.08838834764831845f;

  STAGE(0, 0);
  STAGE(1, 64);
  __builtin_amdgcn_sched_barrier(0);
  asm volatile("s_waitcnt vmcnt(4)" ::: "memory");
  __builtin_amdgcn_s_barrier();
  __builtin_amdgcn_sched_barrier(0);

  for (int s = 0; s < nsteps; ++s){
    const int kv0 = s*64;
    const char* kb = lds + (s&1)*16384;
    const char* vb = lds + 32768 + (s&1)*16384;
    if (kv0 <= qbase){
      const bool diag = (kv0 + 64 > qbase);
      const int kvrel = kv0 - qbase;               // <= 0
      f32x4 sc[2][4] = {};
      #pragma unroll
      for (int n=0;n<4;n++){
        short8 kf[4];
        #pragma unroll
        for (int kc=0;kc<4;kc++)
          kf[kc] = *(const short8*)(kb + (n*16 + l15)*256 + ((kc*64 + l4*16) ^ swzm));
        #pragma unroll
        for (int m=0;m<2;m++)
          #pragma unroll
          for (int kc=0;kc<4;kc++)
            sc[m][n] = __builtin_amdgcn_mfma_f32_16x16x32_bf16(qf[m][kc], kf[kc], sc[m][n], 0,0,0);
      }
      float alpha_[2][4];
      #pragma unroll
      for (int m=0;m<2;m++)
        #pragma unroll
        for (int j=0;j<4;j++){
          const int qr = 16*m + 4*l4 + j;
          float a[4];
          #pragma unroll
          for (int n=0;n<4;n++){
            a[n] = sc[m][n][j]*scale;
            if (diag && (kvrel + n*16 + l15 > qr)) a[n] = -1e30f;
          }
          float mx = fmaxf(fmaxf(a[0],a[1]), fmaxf(a[2],a[3]));
          #pragma unroll
          for (int o=1;o<16;o<<=1) mx = fmaxf(mx, __shfl_xor(mx, o));
          const float mn = fmaxf(mrow[m][j], mx);
          const float al = __expf(mrow[m][j] - mn);
          mrow[m][j] = mn;
          alpha_[m][j] = al;
          __hip_bfloat16* pr = (__hip_bfloat16*)(plbase + qr*144) + l15;
          #pragma unroll
          for (int n=0;n<4;n++) pr[n*16] = f2bf(__expf(a[n] - mn));
        }
      #pragma unroll
      for (int m=0;m<2;m++)
        #pragma unroll
        for (int db=0;db<9;db++)
          #pragma unroll
          for (int j=0;j<4;j++)
            accO[m][db][j] *= alpha_[m][j];
      asm volatile("s_waitcnt lgkmcnt(0)" ::: "memory");
      __builtin_amdgcn_sched_barrier(0);
      short8 pa[2][2];
      #pragma unroll
      for (int m=0;m<2;m++)
        #pragma unroll
        for (int ks=0;ks<2;ks++)
          pa[m][ks] = *(const short8*)(plbase + (m*16 + l15)*144 + ks*64 + l4*16);
      #pragma unroll
      for (int db=0;db<8;db++){
        #pragma unroll
        for (int ks=0;ks<2;ks++){
          short8 vf = *(const short8*)(vb + (db*16 + l15)*128 + ((ks*64 + l4*16) ^ swzm));
          #pragma unroll
          for (int m=0;m<2;m++)
            accO[m][db] = __builtin_amdgcn_mfma_f32_16x16x32_bf16(pa[m][ks], vf, accO[m][db], 0,0,0);
        }
      }
      #pragma unroll
      for (int ks=0;ks<2;ks++)
        #pragma unroll
        for (int m=0;m<2;m++)
          accO[m][8] = __builtin_amdgcn_mfma_f32_16x16x32_bf16(pa[m][ks], of, accO[m][8], 0,0,0);
    }
    __builtin_amdgcn_sched_barrier(0);
    __builtin_amdgcn_s_barrier();
    __builtin_amdgcn_sched_barrier(0);
    if (s + 2 < nsteps){
      STAGE(s&1, (s+2)*64);
      __builtin_amdgcn_sched_barrier(0);
      asm volatile("s_waitcnt vmcnt(4)" ::: "memory");
    } else {
      asm volatile("s_waitcnt vmcnt(0)" ::: "memory");
    }
    __builtin_amdgcn_s_barrier();
    __builtin_amdgcn_sched_barrier(0);
  }

  // broadcast denominator (held by l15==0 lanes of accO[m][8]) and write out
  #pragma unroll
  for (int m=0;m<2;m++){
    float lr[4];
    #pragma unroll
    for (int j=0;j<4;j++) lr[j] = __shfl(accO[m][8][j], l4*16);
    #pragma unroll
    for (int db=0;db<8;db++)
      #pragma unroll
      for (int j=0;j<4;j++){
        const int tg = qbase + 16*m + 4*l4 + j;
        const int d  = 16*db + l15;
        Y[((size_t)b*2048 + tg)*2048 + h*128 + d] = f2bf(accO[m][db][j] / lr[j]);
      }
  }
}

// ---------------- launcher ----------------
extern "C" void kernel_launch(void* const* d_in, const int* in_sizes, int n_in,
                              void* d_out, int out_size, void* d_ws, size_t ws_size,
                              hipStream_t stream)
{
  const float* x    = (const float*)d_in[0];
  const float* cosT = (const float*)d_in[1];
  const float* sinT = (const float*)d_in[2];
  const float* ln1w = (const float*)d_in[3];
  const float* ln1b = (const float*)d_in[4];
  const float* ln2w = (const float*)d_in[5];
  const float* ln2b = (const float*)d_in[6];
  const float* Wqkv = (const float*)d_in[7];
  const float* Wo   = (const float*)d_in[8];
  const float* W1   = (const float*)d_in[9];
  const float* W2   = (const float*)d_in[10];
  const float* W3   = (const float*)d_in[11];
  float* out = (float*)d_out;

  if (ws_size < 150994944) return;   // diagnostic: absmax==7.625 -> ws too small
  char* ws = (char*)d_ws;
  __hip_bfloat16* WT   = (__hip_bfloat16*)(ws);                  // [0,32M)
  __hip_bfloat16* abf  = (__hip_bfloat16*)(ws + 33554432);       // [32M,48M)
  __hip_bfloat16* qkvb = (__hip_bfloat16*)(ws + 50331648);       // [48M,96M)
  __hip_bfloat16* Yb   = (__hip_bfloat16*)(ws + 50331648);
  __hip_bfloat16* sub  = (__hip_bfloat16*)(ws + 50331648);       // [48M,112M) after attn
  __hip_bfloat16* Qb   = (__hip_bfloat16*)(ws + 100663296);
  __hip_bfloat16* Kb   = (__hip_bfloat16*)(ws + 117440512);
  __hip_bfloat16* Vtb  = (__hip_bfloat16*)(ws + 134217728);
  float*          x2   = out;

  hipFuncSetAttribute(reinterpret_cast<const void*>(&gemm256<4,256>),
                      hipFuncAttributeMaxDynamicSharedMemorySize, 131072);
  hipFuncSetAttribute(reinterpret_cast<const void*>(&gemm256<2,256>),
                      hipFuncAttributeMaxDynamicSharedMemorySize, 131072);
  hipFuncSetAttribute(reinterpret_cast<const void*>(&gemm256<3,256>),
                      hipFuncAttributeMaxDynamicSharedMemorySize, 131072);
  hipFuncSetAttribute(reinterpret_cast<const void*>(&gemm256<1,128>),
                      hipFuncAttributeMaxDynamicSharedMemorySize, 98304);
  hipFuncSetAttribute(reinterpret_cast<const void*>(&attn_k),
                      hipFuncAttributeMaxDynamicSharedMemorySize, 102400);

  ln_k<<<4096,256,0,stream>>>(x, ln1w, ln1b, abf);
  wtrans<<<dim3(192,64),256,0,stream>>>(Wqkv, WT, 2048, 6144);
  gemm256<4,256><<<384,512,131072,stream>>>(abf, WT, qkvb, nullptr, nullptr, nullptr, 4096, 6144, 2048, 24);
  ropepack<<<dim3(32,32),256,0,stream>>>(qkvb, cosT, sinT, Qb, Kb, Vtb);
  attn_k<<<dim3(32,8),512,102400,stream>>>(Qb, Kb, Vtb, Yb);
  wtrans<<<dim3(64,64),256,0,stream>>>(Wo, WT, 2048, 2048);
  gemm256<1,128><<<256,512,98304,stream>>>(Yb, WT, nullptr, x2, x, nullptr, 4096, 2048, 2048, 8);
  ln_k<<<4096,256,0,stream>>>(x2, ln2w, ln2b, abf);
  wtrans<<<dim3(256,64),256,0,stream>>>(W1, WT, 2048, 8192);
  gemm256<2,256><<<512,512,131072,stream>>>(abf, WT, sub, nullptr, nullptr, nullptr, 4096, 8192, 2048, 32);
  wtrans<<<dim3(256,64),256,0,stream>>>(W2, WT, 2048, 8192);
  gemm256<3,256><<<512,512,131072,stream>>>(abf, WT, sub, nullptr, nullptr, sub, 4096, 8192, 2048, 32);
  wtrans<<<dim3(64,256),256,0,stream>>>(W3, WT, 8192, 2048);
  gemm256<1,128><<<256,512,98304,stream>>>(sub, WT, nullptr, out, x2, nullptr, 4096, 2048, 8192, 8);
}